// Round 2
// baseline (34.736 us; speedup 1.0000x reference)
//
#include <hip/hip_runtime.h>

#define B_   16
#define C_   3
#define H_   64
#define W_   64
#define K_   32
#define S_   16
#define P_   3600
#define IMG  (C_*H_*W_)   // 12288 pixels per batch image

// ---------------- kernel 1: transpose x (B,C,H,W) f32 -> xt (C,H,W,B) f32 --
__global__ __launch_bounds__(256) void transpose_x_kernel(
    const float* __restrict__ x, float* __restrict__ xt)
{
    int chw = blockIdx.x * blockDim.x + threadIdx.x;
    if (chw >= IMG) return;
    float v[16];
#pragma unroll
    for (int b = 0; b < 16; ++b)
        v[b] = x[b * IMG + chw];
    float4* dst = (float4*)(xt + (size_t)chw * 16);
    dst[0] = make_float4(v[0],  v[1],  v[2],  v[3]);
    dst[1] = make_float4(v[4],  v[5],  v[6],  v[7]);
    dst[2] = make_float4(v[8],  v[9],  v[10], v[11]);
    dst[3] = make_float4(v[12], v[13], v[14], v[15]);
}

// ---------------- kernel 2: coefs = softmax(w) @ M, stored [k][31][4] f32 ---
__global__ __launch_bounds__(256) void coef_kernel(
    const float* __restrict__ w0, const float* __restrict__ w1,
    const float* __restrict__ w2, const float* __restrict__ w3,
    const float* __restrict__ w4, float* __restrict__ coef)
{
    int t = blockIdx.x * blockDim.x + threadIdx.x;
    if (t >= 31 * K_) return;
    int node = t >> 5;     // 0..30
    int k    = t & 31;

    const float* w; int i;
    if      (node < 16) { w = w0; i = node;      }
    else if (node < 24) { w = w1; i = node - 16; }
    else if (node < 28) { w = w2; i = node - 24; }
    else if (node < 30) { w = w3; i = node - 28; }
    else                { w = w4; i = 0;         }

    const float* src = w + ((size_t)i * K_ + k) * 16;
    float l[16];
    float m = -1e30f;
#pragma unroll
    for (int s = 0; s < 16; ++s) { l[s] = src[s]; m = fmaxf(m, l[s]); }
    float sum = 0.f;
#pragma unroll
    for (int s = 0; s < 16; ++s) { l[s] = expf(l[s] - m); sum += l[s]; }
    float inv = 1.f / sum;

    const float M[16][4] = {
        {0,0,0,0},{0,0,0,1},{0,1,0,-1},{0,1,0,0},
        {0,0,1,-1},{0,0,1,0},{0,1,1,-2},{0,1,1,-1},
        {1,-1,-1,1},{1,-1,-1,2},{1,0,-1,0},{1,0,-1,1},
        {1,-1,0,0},{1,-1,0,1},{1,0,0,-1},{1,0,0,0}};

    float c0 = 0.f, c1 = 0.f, c2 = 0.f, c3 = 0.f;
#pragma unroll
    for (int s = 0; s < 16; ++s) {
        float pr = l[s] * inv;
        c0 += pr * M[s][0]; c1 += pr * M[s][1];
        c2 += pr * M[s][2]; c3 += pr * M[s][3];
    }
    ((float4*)coef)[(size_t)k * 31 + node] = make_float4(c0, c1, c2, c3);
}

// ---------------- kernel 3: main gather + gate-tree ------------------------
// Thread mapping: quad of 4 lanes shares one (k,p); lane e in quad handles
// batches 4e..4e+3 (one float4 of the B-innermost xt line). A gathered 64B
// line (16 batches of one pixel) is fetched exactly once per quad, coalesced.
__global__ __launch_bounds__(256) void logic_main_kernel(
    const int* __restrict__ ah, const int* __restrict__ aw, const int* __restrict__ ac,
    const int* __restrict__ bh, const int* __restrict__ bw, const int* __restrict__ bc,
    const float* __restrict__ xt, const float* __restrict__ coef,
    float* __restrict__ out)
{
    const int k   = blockIdx.x;
    const int tid = threadIdx.x;
    const int e   = tid & 3;        // batch-group (4 batches)
    const int p   = blockIdx.y * 64 + (tid >> 2);

    __shared__ float4 cf[31];
    if (tid < 31)
        cf[tid] = ((const float4*)coef)[(size_t)k * 31 + tid];
    __syncthreads();
    if (p >= P_) return;

    const int ib = (k * P_ + p) * 16;

    // cooperative index load: lane e of the quad loads s = 4e..4e+3
    int offA4[4], offB4[4];
    {
        int4 h4 = ((const int4*)(ah + ib))[e];
        int4 w4 = ((const int4*)(aw + ib))[e];
        int4 c4 = ((const int4*)(ac + ib))[e];
        offA4[0] = (c4.x*4096 + h4.x*64 + w4.x) * 16;
        offA4[1] = (c4.y*4096 + h4.y*64 + w4.y) * 16;
        offA4[2] = (c4.z*4096 + h4.z*64 + w4.z) * 16;
        offA4[3] = (c4.w*4096 + h4.w*64 + w4.w) * 16;
        int4 g4 = ((const int4*)(bh + ib))[e];
        int4 v4 = ((const int4*)(bw + ib))[e];
        int4 d4 = ((const int4*)(bc + ib))[e];
        offB4[0] = (d4.x*4096 + g4.x*64 + v4.x) * 16;
        offB4[1] = (d4.y*4096 + g4.y*64 + v4.y) * 16;
        offB4[2] = (d4.z*4096 + g4.z*64 + v4.z) * 16;
        offB4[3] = (d4.w*4096 + g4.w*64 + v4.w) * 16;
    }

    const int qb = (tid & 63) & ~3;   // quad base lane within wave

    float v[4][16];                    // [batch-in-group][leaf]
#pragma unroll
    for (int s = 0; s < 16; ++s) {
        int oa = __shfl(offA4[s & 3], qb + (s >> 2), 64);
        int ob = __shfl(offB4[s & 3], qb + (s >> 2), 64);
        float4 av = *(const float4*)(xt + oa + e * 4);
        float4 bv = *(const float4*)(xt + ob + e * 4);
        float4 c  = cf[s];
        v[0][s] = c.x + c.y*av.x + c.z*bv.x + c.w*(av.x*bv.x);
        v[1][s] = c.x + c.y*av.y + c.z*bv.y + c.w*(av.y*bv.y);
        v[2][s] = c.x + c.y*av.z + c.z*bv.z + c.w*(av.z*bv.z);
        v[3][s] = c.x + c.y*av.w + c.z*bv.w + c.w*(av.w*bv.w);
    }

#pragma unroll
    for (int j = 0; j < 4; ++j) {
#pragma unroll
        for (int i = 0; i < 8; ++i) {
            float4 c = cf[16 + i];
            float a = v[j][2*i], b = v[j][2*i+1];
            v[j][i] = c.x + c.y*a + c.z*b + c.w*(a*b);
        }
#pragma unroll
        for (int i = 0; i < 4; ++i) {
            float4 c = cf[24 + i];
            float a = v[j][2*i], b = v[j][2*i+1];
            v[j][i] = c.x + c.y*a + c.z*b + c.w*(a*b);
        }
#pragma unroll
        for (int i = 0; i < 2; ++i) {
            float4 c = cf[28 + i];
            float a = v[j][2*i], b = v[j][2*i+1];
            v[j][i] = c.x + c.y*a + c.z*b + c.w*(a*b);
        }
        float4 c = cf[30];
        float a = v[j][0], b = v[j][1];
        float r = c.x + c.y*a + c.z*b + c.w*(a*b);
        out[((size_t)(e*4 + j) * K_ + k) * P_ + p] = r;
    }
}

extern "C" void kernel_launch(void* const* d_in, const int* in_sizes, int n_in,
                              void* d_out, int out_size, void* d_ws, size_t ws_size,
                              hipStream_t stream) {
    const float* x  = (const float*)d_in[0];
    const int* ah = (const int*)d_in[1];
    const int* aw = (const int*)d_in[2];
    const int* ac = (const int*)d_in[3];
    const int* bh = (const int*)d_in[4];
    const int* bw = (const int*)d_in[5];
    const int* bc = (const int*)d_in[6];
    const float* w0 = (const float*)d_in[7];
    const float* w1 = (const float*)d_in[8];
    const float* w2 = (const float*)d_in[9];
    const float* w3 = (const float*)d_in[10];
    const float* w4 = (const float*)d_in[11];
    float* out = (float*)d_out;

    float* xt   = (float*)d_ws;                  // IMG*16 floats = 3.0 MiB
    float* coef = xt + (size_t)IMG * 16;         // 31*32*4 floats = 15.5 KiB

    transpose_x_kernel<<<(IMG + 255) / 256, 256, 0, stream>>>(x, xt);
    coef_kernel<<<(31 * K_ + 255) / 256, 256, 0, stream>>>(w0, w1, w2, w3, w4, coef);

    dim3 grid(K_, (P_ + 63) / 64);
    logic_main_kernel<<<grid, 256, 0, stream>>>(ah, aw, ac, bh, bw, bc, xt, coef, out);
}

// Round 3
// 31.754 us; speedup vs baseline: 1.0939x; 1.0939x over previous
//
#include <hip/hip_runtime.h>

#define B_   16
#define C_   3
#define H_   64
#define W_   64
#define K_   32
#define S_   16
#define OH_  60
#define OW_  60
#define P_   3600
#define IMG  (C_*H_*W_)      // 12288 pixels per batch image
#define XT_FLOATS (IMG*16)   // 196608
#define XT_PAD    4096       // slack for ow/rw overhang reads (helper lanes)

// ---------------- prep kernel: transpose + coefs + base-offset decode ------
// blocks 0..47   : transpose x (B,C,H,W) -> xt (C,H,W,B)
// blocks 48..51  : coef[k][node] = softmax(w_node_k) @ M   (992 gates)
// blocks 52..53  : baseA/baseB[k*16+s] from p=0 slice of index arrays
__global__ __launch_bounds__(256) void prep_kernel(
    const float* __restrict__ x,
    const int* __restrict__ ah, const int* __restrict__ aw, const int* __restrict__ ac,
    const int* __restrict__ bh, const int* __restrict__ bw, const int* __restrict__ bc,
    const float* __restrict__ w0, const float* __restrict__ w1,
    const float* __restrict__ w2, const float* __restrict__ w3,
    const float* __restrict__ w4,
    float* __restrict__ xt, float* __restrict__ coef,
    int* __restrict__ baseA, int* __restrict__ baseB)
{
    const int blk = blockIdx.x;
    const int tid = threadIdx.x;

    if (blk < 48) {                      // ---- transpose ----
        int chw = blk * 256 + tid;       // 48*256 == 12288 exactly
        float v[16];
#pragma unroll
        for (int b = 0; b < 16; ++b)
            v[b] = x[b * IMG + chw];
        float4* dst = (float4*)(xt + (size_t)chw * 16);
        dst[0] = make_float4(v[0],  v[1],  v[2],  v[3]);
        dst[1] = make_float4(v[4],  v[5],  v[6],  v[7]);
        dst[2] = make_float4(v[8],  v[9],  v[10], v[11]);
        dst[3] = make_float4(v[12], v[13], v[14], v[15]);
        return;
    }
    if (blk < 52) {                      // ---- coefs ----
        int t = (blk - 48) * 256 + tid;
        if (t >= 31 * K_) return;
        int node = t >> 5;               // 0..30
        int k    = t & 31;
        const float* w; int i;
        if      (node < 16) { w = w0; i = node;      }
        else if (node < 24) { w = w1; i = node - 16; }
        else if (node < 28) { w = w2; i = node - 24; }
        else if (node < 30) { w = w3; i = node - 28; }
        else                { w = w4; i = 0;         }
        const float* src = w + ((size_t)i * K_ + k) * 16;
        float l[16];
        float m = -1e30f;
#pragma unroll
        for (int s = 0; s < 16; ++s) { l[s] = src[s]; m = fmaxf(m, l[s]); }
        float sum = 0.f;
#pragma unroll
        for (int s = 0; s < 16; ++s) { l[s] = expf(l[s] - m); sum += l[s]; }
        float inv = 1.f / sum;
        const float M[16][4] = {
            {0,0,0,0},{0,0,0,1},{0,1,0,-1},{0,1,0,0},
            {0,0,1,-1},{0,0,1,0},{0,1,1,-2},{0,1,1,-1},
            {1,-1,-1,1},{1,-1,-1,2},{1,0,-1,0},{1,0,-1,1},
            {1,-1,0,0},{1,-1,0,1},{1,0,0,-1},{1,0,0,0}};
        float c0 = 0.f, c1 = 0.f, c2 = 0.f, c3 = 0.f;
#pragma unroll
        for (int s = 0; s < 16; ++s) {
            float pr = l[s] * inv;
            c0 += pr * M[s][0]; c1 += pr * M[s][1];
            c2 += pr * M[s][2]; c3 += pr * M[s][3];
        }
        ((float4*)coef)[(size_t)k * 31 + node] = make_float4(c0, c1, c2, c3);
        return;
    }
    {                                    // ---- base offsets (p = 0 slice) ----
        int i = (blk - 52) * 256 + tid;
        if (i >= K_ * S_) return;
        int k = i >> 4, s = i & 15;
        int idx = k * (P_ * 16) + s;     // (k*P + 0)*16 + s
        baseA[i] = (ac[idx] * 4096 + ah[idx] * 64 + aw[idx]) * 16;
        baseB[i] = (bc[idx] * 4096 + bh[idx] * 64 + bw[idx]) * 16;
    }
}

// ---------------- main kernel: structured gather + gate tree ---------------
// grid (oh=60, k=32), 256 threads. lane l in wave wv: ow = wv*16 + (l&15),
// batch-group e = l>>4 (batches 4e..4e+3). Per s each wave's two float4
// gathers form one contiguous 1KB run of xt -> fully coalesced, L2-resident.
__global__ __launch_bounds__(256) void logic_main_kernel(
    const float* __restrict__ xt, const float* __restrict__ coef,
    const int* __restrict__ baseA, const int* __restrict__ baseB,
    float* __restrict__ out)
{
    const int oh = blockIdx.x;
    const int k  = blockIdx.y;
    const int tid = threadIdx.x;

    __shared__ float4 cf[31];
    __shared__ int bA[16], bB[16];
    if (tid < 31)                 cf[tid]      = ((const float4*)coef)[(size_t)k * 31 + tid];
    else if (tid >= 32 && tid < 48) bA[tid-32] = baseA[k * 16 + (tid - 32)];
    else if (tid >= 48 && tid < 64) bB[tid-48] = baseB[k * 16 + (tid - 48)];
    __syncthreads();

    const int l  = tid & 63;
    const int wv = tid >> 6;
    const int ow = wv * 16 + (l & 15);   // 0..63 (>=60 are helper lanes)
    const int e  = l >> 4;               // batch group
    const int pix = (oh * 64 + ow) * 16 + e * 4;

    float v[4][16];                      // [batch-in-group][leaf]
#pragma unroll
    for (int s = 0; s < 16; ++s) {
        float4 av = *(const float4*)(xt + bA[s] + pix);
        float4 bv = *(const float4*)(xt + bB[s] + pix);
        float4 c  = cf[s];
        v[0][s] = c.x + c.y*av.x + c.z*bv.x + c.w*(av.x*bv.x);
        v[1][s] = c.x + c.y*av.y + c.z*bv.y + c.w*(av.y*bv.y);
        v[2][s] = c.x + c.y*av.z + c.z*bv.z + c.w*(av.z*bv.z);
        v[3][s] = c.x + c.y*av.w + c.z*bv.w + c.w*(av.w*bv.w);
    }

    const bool valid = (ow < OW_);
#pragma unroll
    for (int j = 0; j < 4; ++j) {
#pragma unroll
        for (int i = 0; i < 8; ++i) {
            float4 c = cf[16 + i];
            float a = v[j][2*i], b = v[j][2*i+1];
            v[j][i] = c.x + c.y*a + c.z*b + c.w*(a*b);
        }
#pragma unroll
        for (int i = 0; i < 4; ++i) {
            float4 c = cf[24 + i];
            float a = v[j][2*i], b = v[j][2*i+1];
            v[j][i] = c.x + c.y*a + c.z*b + c.w*(a*b);
        }
#pragma unroll
        for (int i = 0; i < 2; ++i) {
            float4 c = cf[28 + i];
            float a = v[j][2*i], b = v[j][2*i+1];
            v[j][i] = c.x + c.y*a + c.z*b + c.w*(a*b);
        }
        float4 c = cf[30];
        float a = v[j][0], b = v[j][1];
        float r = c.x + c.y*a + c.z*b + c.w*(a*b);
        if (valid)
            out[((size_t)(e*4 + j) * K_ + k) * P_ + oh * OW_ + ow] = r;
    }
}

extern "C" void kernel_launch(void* const* d_in, const int* in_sizes, int n_in,
                              void* d_out, int out_size, void* d_ws, size_t ws_size,
                              hipStream_t stream) {
    const float* x  = (const float*)d_in[0];
    const int* ah = (const int*)d_in[1];
    const int* aw = (const int*)d_in[2];
    const int* ac = (const int*)d_in[3];
    const int* bh = (const int*)d_in[4];
    const int* bw = (const int*)d_in[5];
    const int* bc = (const int*)d_in[6];
    const float* w0 = (const float*)d_in[7];
    const float* w1 = (const float*)d_in[8];
    const float* w2 = (const float*)d_in[9];
    const float* w3 = (const float*)d_in[10];
    const float* w4 = (const float*)d_in[11];
    float* out = (float*)d_out;

    float* xt   = (float*)d_ws;                         // 196608 + pad floats
    float* coef = xt + XT_FLOATS + XT_PAD;              // 31*32*4 floats
    int*  baseA = (int*)(coef + 31 * K_ * 4);           // 512 ints
    int*  baseB = baseA + K_ * S_;                      // 512 ints

    prep_kernel<<<54, 256, 0, stream>>>(x, ah, aw, ac, bh, bw, bc,
                                        w0, w1, w2, w3, w4,
                                        xt, coef, baseA, baseB);

    dim3 grid(OH_, K_);
    logic_main_kernel<<<grid, 256, 0, stream>>>(xt, coef, baseA, baseB, out);
}